// Round 4
// baseline (365.954 us; speedup 1.0000x reference)
//
#include <hip/hip_runtime.h>
#include <hip/hip_bf16.h>

// Problem constants
#define B_ 4
#define S_ 2048
#define H_ 1024
#define NH_ 16
#define HD_ 64
// HD^-0.5 * log2(e), folded into Wq at cast time -> QK MFMA emits log2-domain
#define QSCALE 0.1803368801111204f

typedef __bf16 bf16_t;
typedef bf16_t bf16x8 __attribute__((ext_vector_type(8)));
typedef bf16_t bf16x4 __attribute__((ext_vector_type(4)));
typedef bf16_t bf16x2t __attribute__((ext_vector_type(2)));
typedef float f32x4 __attribute__((ext_vector_type(4)));
typedef unsigned u32x2 __attribute__((ext_vector_type(2)));
typedef unsigned u32x4 __attribute__((ext_vector_type(4)));

__device__ __forceinline__ f32x4 mfma16(bf16x8 a, bf16x8 b, f32x4 c) {
  return __builtin_amdgcn_mfma_f32_16x16x32_bf16(a, b, c, 0, 0, 0);
}

// Raw v_exp_f32 (no denormal-guard sequence). Inputs below -126 flush to 0,
// which is exactly right for softmax tails.
__device__ __forceinline__ float fast_exp2(float x) {
#if __has_builtin(__builtin_amdgcn_exp2f)
  return __builtin_amdgcn_exp2f(x);
#else
  float r;
  asm("v_exp_f32 %0, %1" : "=v"(r) : "v"(x));
  return r;
#endif
}

// async 16B global->LDS. lds ptr must be wave-uniform; HW adds lane*16.
__device__ __forceinline__ void gll16(const bf16_t* g, bf16_t* l) {
  __builtin_amdgcn_global_load_lds(
      (const __attribute__((address_space(1))) void*)g,
      (__attribute__((address_space(3))) void*)l, 16, 0, 0);
}

// Read a 16B A/B fragment from a [rows][64] bf16 LDS tile whose 16B chunks
// are XOR-swizzled: LDS[row][slot] holds global chunk slot^(row&7).
__device__ __forceinline__ bf16x8 frag64(const bf16_t* lds, int row,
                                         int kchunk) {
  return *(const bf16x8*)((const char*)lds + row * 128 +
                          ((kchunk ^ (row & 7)) << 4));
}

// Stage a 128x64 bf16 tile (rows from gbase, row stride gstride elems) into
// a 16KB LDS tile with the XOR chunk swizzle. 4 waves x 4 segs x 1KB.
__device__ __forceinline__ void stage128(const bf16_t* gbase, int gstride,
                                         bf16_t* lds, int w, int lane) {
#pragma unroll
  for (int j = 0; j < 4; ++j) {
    int seg = w * 4 + j;
    int row = seg * 8 + (lane >> 3);
    int chunk = (lane & 7) ^ (row & 7);
    gll16(gbase + (size_t)row * gstride + chunk * 8, lds + seg * 512);
  }
}

// ---------------------------------------------------------------------------
// Cast fp32 -> bf16 for X (8M elems) and the 4 weight matrices (1M each).
// Wq additionally scaled by QSCALE so scores come out in log2 domain.
// Also emits maskl = mask * log2(e) (fp32, B*S).
// ---------------------------------------------------------------------------
__global__ __launch_bounds__(256) void cvt_all(
    const float* __restrict__ X, const float* __restrict__ Wq,
    const float* __restrict__ Wk, const float* __restrict__ Wv,
    const float* __restrict__ Wo, const float* __restrict__ mask,
    bf16_t* __restrict__ Xb, bf16_t* __restrict__ Wqb,
    bf16_t* __restrict__ Wkb, bf16_t* __restrict__ Wvb,
    bf16_t* __restrict__ Wob, float* __restrict__ maskl) {
  size_t i = ((size_t)blockIdx.x * 256 + threadIdx.x) * 4;
  const float* src;
  bf16_t* dst;
  size_t off;
  float scale = 1.0f;
  if (i < 8388608) {
    src = X; dst = Xb; off = i;
  } else {
    size_t j = i - 8388608;
    if (j >= 4194304) {
      // mask tail: 8192 floats -> maskl (fp32, scaled by log2e)
      size_t mo = j - 4194304;  // grid sized so mo in [0, 8192)
      float4 mv = *(const float4*)(mask + mo);
      const float LOG2E = 1.4426950408889634f;
      float4 ml = {mv.x * LOG2E, mv.y * LOG2E, mv.z * LOG2E, mv.w * LOG2E};
      *(float4*)(maskl + mo) = ml;
      return;
    }
    int w = (int)(j >> 20);
    off = j & 1048575;
    switch (w) {
      case 0: src = Wq; dst = Wqb; scale = QSCALE; break;
      case 1: src = Wk; dst = Wkb; break;
      case 2: src = Wv; dst = Wvb; break;
      default: src = Wo; dst = Wob; break;
    }
  }
  float4 v = *(const float4*)(src + off);
  bf16x4 o = {(bf16_t)(v.x * scale), (bf16_t)(v.y * scale),
              (bf16_t)(v.z * scale), (bf16_t)(v.w * scale)};
  *(bf16x4*)(dst + off) = o;
}

// ---------------------------------------------------------------------------
// GEMM body (m97 structure): 128x128 tile, BK=64, global_load_lds staging,
// XOR-swizzled LDS, 4 waves (2x2), 32 MFMA / BK. setprio kept (R3 showed
// neutral-to-positive ~15us on the GEMM dispatches).
// ---------------------------------------------------------------------------
__device__ __forceinline__ void gemm_core(const bf16_t* __restrict__ A,
                                          const bf16_t* __restrict__ Bw,
                                          int Mb, int Nb, bf16_t* As,
                                          bf16_t* Bs, f32x4 (*acc)[4], int w,
                                          int lane, int quad, int l15, int wm,
                                          int wn) {
  for (int kb = 0; kb < 16; ++kb) {
    stage128(A + (size_t)Mb * 1024 + kb * 64, 1024, As, w, lane);
    stage128(Bw + (size_t)Nb * 1024 + kb * 64, 1024, Bs, w, lane);
    __syncthreads();
#pragma unroll
    for (int kt = 0; kt < 2; ++kt) {
      bf16x8 af[4], bfr[4];
#pragma unroll
      for (int i = 0; i < 4; ++i) {
        af[i] = frag64(As, wm * 64 + i * 16 + l15, kt * 4 + quad);
        bfr[i] = frag64(Bs, wn * 64 + i * 16 + l15, kt * 4 + quad);
      }
      __builtin_amdgcn_s_setprio(1);
#pragma unroll
      for (int mt = 0; mt < 4; ++mt)
#pragma unroll
        for (int nt = 0; nt < 4; ++nt)
          acc[mt][nt] = mfma16(af[mt], bfr[nt], acc[mt][nt]);
      __builtin_amdgcn_s_setprio(0);
    }
    __syncthreads();
  }
}

// ---------------------------------------------------------------------------
// Fused QKV projections, one dispatch. grid (64, 8, 3).
// ---------------------------------------------------------------------------
__global__ __launch_bounds__(256) void gemm_qkv(
    const bf16_t* __restrict__ Xb, const bf16_t* __restrict__ Wqb,
    const bf16_t* __restrict__ Wkb, const bf16_t* __restrict__ Wvb,
    bf16_t* __restrict__ q_ws, bf16_t* __restrict__ k_ws,
    bf16_t* __restrict__ vt_ws) {
  __shared__ __align__(16) bf16_t As[8192];
  __shared__ __align__(16) bf16_t Bs[8192];
  int w = threadIdx.x >> 6, lane = threadIdx.x & 63;
  int quad = lane >> 4, l15 = lane & 15;
  int wm = w >> 1, wn = w & 1;
  int z = blockIdx.z;
  const bf16_t* A = (z == 2) ? Wvb : Xb;
  const bf16_t* Bw = (z == 0) ? Wqb : ((z == 1) ? Wkb : Xb);
  int Mb = (z == 2) ? blockIdx.y * 128 : blockIdx.x * 128;
  int Nb = (z == 2) ? blockIdx.x * 128 : blockIdx.y * 128;
  f32x4 acc[4][4] = {};
  gemm_core(A, Bw, Mb, Nb, As, Bs, acc, w, lane, quad, l15, wm, wn);
  if (z != 2) {
    bf16_t* O = (z == 0) ? q_ws : k_ws;
#pragma unroll
    for (int mt = 0; mt < 4; ++mt) {
      int m0t = Mb + wm * 64 + mt * 16;
#pragma unroll
      for (int nt = 0; nt < 4; ++nt) {
        int n0t = Nb + wn * 64 + nt * 16;
        int h = n0t >> 6, d = (n0t & 63) + l15;
#pragma unroll
        for (int r = 0; r < 4; ++r) {
          int tok = m0t + quad * 4 + r;
          int b = tok >> 11, s = tok & 2047;
          O[(((size_t)b * NH_ + h) * S_ + s) * HD_ + d] = (bf16_t)acc[mt][nt][r];
        }
      }
    }
  } else {
#pragma unroll
    for (int mt = 0; mt < 4; ++mt) {
      int m0t = Mb + wm * 64 + mt * 16;
#pragma unroll
      for (int nt = 0; nt < 4; ++nt) {
        int n0t = Nb + wn * 64 + nt * 16;
#pragma unroll
        for (int r = 0; r < 4; ++r) {
          int dg = m0t + quad * 4 + r;
          int hh = dg >> 6, d = dg & 63;
          int tok = n0t + l15;
          int b = tok >> 11, s = tok & 2047;
          vt_ws[((size_t)(b * NH_ + hh) * HD_ + d) * S_ + s] =
              (bf16_t)acc[mt][nt][r];
        }
      }
    }
  }
}

// ---------------------------------------------------------------------------
// Output projection: out = attn @ Wo^T, fp32 [M,1024]. grid (64, 8).
// ---------------------------------------------------------------------------
__global__ __launch_bounds__(256) void gemm_out(
    const bf16_t* __restrict__ A, const bf16_t* __restrict__ Bw,
    float* __restrict__ out) {
  __shared__ __align__(16) bf16_t As[8192];
  __shared__ __align__(16) bf16_t Bs[8192];
  int w = threadIdx.x >> 6, lane = threadIdx.x & 63;
  int quad = lane >> 4, l15 = lane & 15;
  int wm = w >> 1, wn = w & 1;
  int Mb = blockIdx.x * 128, Nb = blockIdx.y * 128;
  f32x4 acc[4][4] = {};
  gemm_core(A, Bw, Mb, Nb, As, Bs, acc, w, lane, quad, l15, wm, wn);
#pragma unroll
  for (int mt = 0; mt < 4; ++mt) {
    int m0t = Mb + wm * 64 + mt * 16;
#pragma unroll
    for (int nt = 0; nt < 4; ++nt) {
      int n0t = Nb + wn * 64 + nt * 16;
#pragma unroll
      for (int r = 0; r < 4; ++r)
        out[(size_t)(m0t + quad * 4 + r) * 1024 + n0t + l15] = acc[mt][nt][r];
    }
  }
}

// ---------------------------------------------------------------------------
// Flash attention. R4: DEEP PREFETCH. R3 post-mortem: trimming softmax VALU
// exposed a vmcnt stall at the top of each iteration (all utils dropped,
// dur rose) -- the c+2 prefetch had <1 compute-phase of latency cover, and
// R2's fat exp2 sequence had been covering HBM latency by accident.
// Now two named register sets (A/B, loop unrolled x2 so all reg indexing is
// compile-time -- scratch rule): iter c writes set (chunk c+1) to LDS, then
// refills the SAME set with chunk c+3. Issue->use distance = 2 full
// iterations (~2x the old cover). +16 VGPR (~100 total, inside 128 tier).
// setprio REMOVED in attn (lockstep-barrier regime: m190 null/negative).
// Kept from R2/R3: P-in-register permlane transpose (bank conflicts 0),
// fast_exp2, maskl pre-scale, launch_bounds(256,3) (NOT 4 -- R1 spill).
// grid (S/128, B*NH), block 256; LDS 32.8KB.
// ---------------------------------------------------------------------------
#define ATTN_STEP(c, KR, VR, CUR)                                             \
  do {                                                                        \
    /* (1) write chunk c+1 (in KR/VR, loaded 2 iters ago) to buf CUR^1 */     \
    if ((c) + 1 < 32) {                                                       \
      *(bf16x8*)(&Ks[(CUR) ^ 1][0] + soff[0]) = KR[0];                        \
      *(bf16x8*)(&Vs[(CUR) ^ 1][0] + soff[0]) = VR[0];                        \
      *(bf16x8*)(&Ks[(CUR) ^ 1][0] + soff[1]) = KR[1];                        \
      *(bf16x8*)(&Vs[(CUR) ^ 1][0] + soff[1]) = VR[1];                        \
    }                                                                         \
    /* (2) refill KR/VR with chunk c+3 (2 iterations of latency cover) */     \
    if ((c) + 3 < 32) {                                                       \
      const bf16_t* Kc = Kh + (size_t)((c) + 3) * 64 * HD_;                   \
      const bf16_t* Vc = Vh + (size_t)((c) + 3) * 64;                         \
      KR[0] = *(const bf16x8*)(Kc + (size_t)srow[0] * HD_ + schunk[0] * 8);   \
      VR[0] = *(const bf16x8*)(Vc + (size_t)srow[0] * S_ + schunk[0] * 8);    \
      KR[1] = *(const bf16x8*)(Kc + (size_t)srow[1] * HD_ + schunk[1] * 8);   \
      VR[1] = *(const bf16x8*)(Vc + (size_t)srow[1] * S_ + schunk[1] * 8);    \
    }                                                                         \
    /* mask: consume prefetched regs; prefetch chunk c+1 (log2-domain) */     \
    f32x4 mcur[4];                                                            \
    _Pragma("unroll") for (int mt = 0; mt < 4; ++mt) mcur[mt] = mreg[mt];     \
    if ((c) + 1 < 32) {                                                       \
      _Pragma("unroll") for (int mt = 0; mt < 4; ++mt)                        \
          mreg[mt] =                                                          \
              *(const f32x4*)(mb + ((c) + 1) * 64 + mt * 16 + quad * 4);      \
    }                                                                         \
    /* (3) S^T = K @ Q^T (log2 domain): row=key=mt*16+quad*4+r, col=q */      \
    f32x4 sc[4][2] = {};                                                      \
    _Pragma("unroll") for (int kt = 0; kt < 2; ++kt) {                        \
      bf16x8 kf[4];                                                           \
      _Pragma("unroll") for (int mt = 0; mt < 4; ++mt)                        \
          kf[mt] = frag64(Ks[CUR], mt * 16 + l15, kt * 4 + quad);             \
      _Pragma("unroll") for (int mt = 0; mt < 4; ++mt)                        \
          _Pragma("unroll") for (int nt = 0; nt < 2; ++nt)                    \
              sc[mt][nt] = mfma16(kf[mt], qf[nt][kt], sc[mt][nt]);            \
    }                                                                         \
    /* P = exp2(s + maskl); pack + quad-transpose in-register; PV MFMA */     \
    _Pragma("unroll") for (int kt = 0; kt < 2; ++kt) {                        \
      unsigned pk[2][2][2];                                                   \
      _Pragma("unroll") for (int mi = 0; mi < 2; ++mi) {                      \
        int mt = kt * 2 + mi;                                                 \
        _Pragma("unroll") for (int nt = 0; nt < 2; ++nt) {                    \
          f32x4 e = sc[mt][nt] + mcur[mt];                                    \
          f32x4 p;                                                            \
          _Pragma("unroll") for (int r = 0; r < 4; ++r)                       \
              p[r] = fast_exp2(e[r]);                                         \
          bf16x2t h0 = {(bf16_t)p[0], (bf16_t)p[1]};                          \
          bf16x2t h1 = {(bf16_t)p[2], (bf16_t)p[3]};                          \
          pk[mi][nt][0] = __builtin_bit_cast(unsigned, h0);                   \
          pk[mi][nt][1] = __builtin_bit_cast(unsigned, h1);                   \
        }                                                                     \
      }                                                                       \
      bf16x8 pf[2];                                                           \
      _Pragma("unroll") for (int nt = 0; nt < 2; ++nt) {                      \
        u32x2 a0 = __builtin_amdgcn_permlane32_swap(pk[0][nt][0],             \
                                                    pk[1][nt][0],             \
                                                    false, false);            \
        u32x2 b0 = __builtin_amdgcn_permlane16_swap(a0.x, a0.y, false,        \
                                                    false);                   \
        u32x2 a1 = __builtin_amdgcn_permlane32_swap(pk[0][nt][1],             \
                                                    pk[1][nt][1],             \
                                                    false, false);            \
        u32x2 b1 = __builtin_amdgcn_permlane16_swap(a1.x, a1.y, false,        \
                                                    false);                   \
        u32x4 pu = {b0.x, b1.x, b0.y, b1.y};                                  \
        pf[nt] = __builtin_bit_cast(bf16x8, pu);                              \
      }                                                                       \
      lc[0] = mfma16(ones, pf[0], lc[0]);                                     \
      lc[1] = mfma16(ones, pf[1], lc[1]);                                     \
      _Pragma("unroll") for (int dt = 0; dt < 4; ++dt) {                      \
        bf16x8 vf = frag64(Vs[CUR], dt * 16 + l15, kt * 4 + quad);            \
        _Pragma("unroll") for (int nt = 0; nt < 2; ++nt)                      \
            oc[dt][nt] = mfma16(vf, pf[nt], oc[dt][nt]);                      \
      }                                                                       \
    }                                                                         \
    /* (4) single barrier: chunk c+1 visible; buf CUR free next iter */       \
    __syncthreads();                                                          \
  } while (0)

__global__ __launch_bounds__(256, 3) void attn_fused(
    const bf16_t* __restrict__ Q, const bf16_t* __restrict__ K,
    const bf16_t* __restrict__ Vt, const float* __restrict__ maskl,
    bf16_t* __restrict__ Oa) {
  __shared__ __align__(16) bf16_t Ks[2][4096];
  __shared__ __align__(16) bf16_t Vs[2][4096];
  int w = threadIdx.x >> 6, lane = threadIdx.x & 63;
  int quad = lane >> 4, l15 = lane & 15;
  int bh = blockIdx.y;
  int b = bh >> 4, h = bh & 15;
  int q0 = blockIdx.x * 128 + w * 32;
  const bf16_t* Qh = Q + (size_t)bh * (S_ * HD_);
  const bf16_t* Kh = K + (size_t)bh * (S_ * HD_);
  const bf16_t* Vh = Vt + (size_t)bh * (HD_ * S_);
  const float* mb = maskl + b * S_;  // already log2-domain
  const bf16_t one_b = (bf16_t)1.0f;
  bf16x8 ones = {one_b, one_b, one_b, one_b, one_b, one_b, one_b, one_b};

  // staging geometry: thread handles segs w*2+j (j=0,1) of each 8KB tile.
  int srow[2], schunk[2], soff[2];
#pragma unroll
  for (int j = 0; j < 2; ++j) {
    int seg = w * 2 + j;
    srow[j] = seg * 8 + (lane >> 3);
    schunk[j] = (lane & 7) ^ (srow[j] & 7);
    soff[j] = seg * 512 + lane * 8;
  }

  // Q B-frags: [n=q=l15][k=d=quad*8+j], nt in {0,1}, kt in {0,1}
  bf16x8 qf[2][2];
#pragma unroll
  for (int nt = 0; nt < 2; ++nt)
#pragma unroll
    for (int kt = 0; kt < 2; ++kt)
      qf[nt][kt] = *(const bf16x8*)(Qh + (size_t)(q0 + nt * 16 + l15) * HD_ +
                                    kt * 32 + quad * 8);

  f32x4 oc[4][2] = {};
  f32x4 lc[2] = {};  // row-sum accumulators via ones-MFMA (rows identical)

  // prologue: chunk0 -> regs -> buf0; chunk1 -> setA; chunk2 -> setB
  bf16x8 krA[2], vrA[2], krB[2], vrB[2];
#pragma unroll
  for (int j = 0; j < 2; ++j) {
    krA[j] = *(const bf16x8*)(Kh + (size_t)srow[j] * HD_ + schunk[j] * 8);
    vrA[j] = *(const bf16x8*)(Vh + (size_t)srow[j] * S_ + schunk[j] * 8);
  }
#pragma unroll
  for (int j = 0; j < 2; ++j) {
    *(bf16x8*)(&Ks[0][0] + soff[j]) = krA[j];
    *(bf16x8*)(&Vs[0][0] + soff[j]) = vrA[j];
  }
#pragma unroll
  for (int j = 0; j < 2; ++j) {
    krA[j] = *(const bf16x8*)(Kh + (size_t)(64 * HD_) +
                              (size_t)srow[j] * HD_ + schunk[j] * 8);
    vrA[j] = *(const bf16x8*)(Vh + 64 + (size_t)srow[j] * S_ + schunk[j] * 8);
  }
#pragma unroll
  for (int j = 0; j < 2; ++j) {
    krB[j] = *(const bf16x8*)(Kh + (size_t)(128 * HD_) +
                              (size_t)srow[j] * HD_ + schunk[j] * 8);
    vrB[j] = *(const bf16x8*)(Vh + 128 + (size_t)srow[j] * S_ + schunk[j] * 8);
  }
  f32x4 mreg[4];
#pragma unroll
  for (int mt = 0; mt < 4; ++mt)
    mreg[mt] = *(const f32x4*)(mb + mt * 16 + quad * 4);
  __syncthreads();

  // main loop, unrolled x2 so register-set selection is compile-time
  for (int cc = 0; cc < 32; cc += 2) {
    ATTN_STEP(cc, krA, vrA, 0);
    ATTN_STEP(cc + 1, krB, vrB, 1);
  }

  // ---- epilogue: O^T/l -> Oa[b, s=q, h*64+d], packed 8B stores ----
  float inv[2] = {1.0f / lc[0][0], 1.0f / lc[1][0]};
#pragma unroll
  for (int dt = 0; dt < 4; ++dt)
#pragma unroll
    for (int nt = 0; nt < 2; ++nt) {
      bf16x4 o4;
#pragma unroll
      for (int r = 0; r < 4; ++r) o4[r] = (bf16_t)(oc[dt][nt][r] * inv[nt]);
      size_t tok = (size_t)b * S_ + q0 + nt * 16 + l15;
      *(bf16x4*)(Oa + tok * H_ + h * HD_ + dt * 16 + quad * 4) = o4;
    }
}

// ---------------------------------------------------------------------------
extern "C" void kernel_launch(void* const* d_in, const int* in_sizes, int n_in,
                              void* d_out, int out_size, void* d_ws,
                              size_t ws_size, hipStream_t stream) {
  const float* hs   = (const float*)d_in[0];
  const float* mask = (const float*)d_in[1];
  const float* Wq   = (const float*)d_in[2];
  const float* Wk   = (const float*)d_in[3];
  const float* Wv   = (const float*)d_in[4];
  const float* Wo   = (const float*)d_in[5];
  float* out = (float*)d_out;

  char* p = (char*)d_ws;
  bf16_t* Xb  = (bf16_t*)p; p += (size_t)8192 * 1024 * 2;
  bf16_t* Wqb = (bf16_t*)p; p += (size_t)1024 * 1024 * 2;
  bf16_t* Wkb = (bf16_t*)p; p += (size_t)1024 * 1024 * 2;
  bf16_t* Wvb = (bf16_t*)p; p += (size_t)1024 * 1024 * 2;
  bf16_t* Wob = (bf16_t*)p; p += (size_t)1024 * 1024 * 2;
  bf16_t* q_ws  = (bf16_t*)p; p += (size_t)8192 * 1024 * 2;  // [B,NH,S,HD]
  bf16_t* k_ws  = (bf16_t*)p; p += (size_t)8192 * 1024 * 2;  // [B,NH,S,HD]
  bf16_t* vt_ws = (bf16_t*)p; p += (size_t)8192 * 1024 * 2;  // [B,NH,HD,S]
  float* maskl = (float*)p; p += (size_t)B_ * S_ * 4;        // log2e-scaled
  bf16_t* attn_b = Xb;  // Xb dead after QKV GEMMs; reuse for attention output

  // grid covers 8M X + 4M weights + 8K mask floats, all /4 per thread
  cvt_all<<<12296, 256, 0, stream>>>(hs, Wq, Wk, Wv, Wo, mask, Xb, Wqb, Wkb,
                                     Wvb, Wob, maskl);
  gemm_qkv<<<dim3(64, 8, 3), 256, 0, stream>>>(Xb, Wqb, Wkb, Wvb, q_ws, k_ws,
                                               vt_ws);
  attn_fused<<<dim3(16, 64), 256, 0, stream>>>(q_ws, k_ws, vt_ws, maskl,
                                               attn_b);
  gemm_out<<<dim3(64, 8), 256, 0, stream>>>(attn_b, Wob, out);
}

// Round 5
// 270.795 us; speedup vs baseline: 1.3514x; 1.3514x over previous
//
#include <hip/hip_runtime.h>
#include <hip/hip_bf16.h>

// Problem constants
#define B_ 4
#define S_ 2048
#define H_ 1024
#define NH_ 16
#define HD_ 64
// HD^-0.5 * log2(e), folded into Wq at cast time -> QK MFMA emits log2-domain
#define QSCALE 0.1803368801111204f

typedef __bf16 bf16_t;
typedef bf16_t bf16x8 __attribute__((ext_vector_type(8)));
typedef bf16_t bf16x4 __attribute__((ext_vector_type(4)));
typedef bf16_t bf16x2t __attribute__((ext_vector_type(2)));
typedef float f32x4 __attribute__((ext_vector_type(4)));
typedef unsigned u32x2 __attribute__((ext_vector_type(2)));
typedef unsigned u32x4 __attribute__((ext_vector_type(4)));

__device__ __forceinline__ f32x4 mfma16(bf16x8 a, bf16x8 b, f32x4 c) {
  return __builtin_amdgcn_mfma_f32_16x16x32_bf16(a, b, c, 0, 0, 0);
}

// Single v_exp_f32 via OCML native (always linked by hipcc; no builtin
// availability gamble, no asm). Flush-to-zero below -126 is exactly right
// for softmax tails. R3/R4 LESSON: the asm-volatile fallback serialized the
// loop and blew up liveness -> spill; never again.
extern "C" __device__ float __ocml_native_exp2_f32(float);
__device__ __forceinline__ float fast_exp2(float x) {
  return __ocml_native_exp2_f32(x);
}

// async 16B global->LDS. lds ptr must be wave-uniform; HW adds lane*16.
__device__ __forceinline__ void gll16(const bf16_t* g, bf16_t* l) {
  __builtin_amdgcn_global_load_lds(
      (const __attribute__((address_space(1))) void*)g,
      (__attribute__((address_space(3))) void*)l, 16, 0, 0);
}

// Read a 16B A/B fragment from a [rows][64] bf16 LDS tile whose 16B chunks
// are XOR-swizzled: LDS[row][slot] holds global chunk slot^(row&7).
__device__ __forceinline__ bf16x8 frag64(const bf16_t* lds, int row,
                                         int kchunk) {
  return *(const bf16x8*)((const char*)lds + row * 128 +
                          ((kchunk ^ (row & 7)) << 4));
}

// Stage a 128x64 bf16 tile (rows from gbase, row stride gstride elems) into
// a 16KB LDS tile with the XOR chunk swizzle. 4 waves x 4 segs x 1KB.
__device__ __forceinline__ void stage128(const bf16_t* gbase, int gstride,
                                         bf16_t* lds, int w, int lane) {
#pragma unroll
  for (int j = 0; j < 4; ++j) {
    int seg = w * 4 + j;
    int row = seg * 8 + (lane >> 3);
    int chunk = (lane & 7) ^ (row & 7);
    gll16(gbase + (size_t)row * gstride + chunk * 8, lds + seg * 512);
  }
}

// ---------------------------------------------------------------------------
// Cast fp32 -> bf16 for X (8M elems) and the 4 weight matrices (1M each).
// Wq additionally scaled by QSCALE so scores come out in log2 domain.
// Also emits maskl = mask * log2(e) (fp32, B*S).
// ---------------------------------------------------------------------------
__global__ __launch_bounds__(256) void cvt_all(
    const float* __restrict__ X, const float* __restrict__ Wq,
    const float* __restrict__ Wk, const float* __restrict__ Wv,
    const float* __restrict__ Wo, const float* __restrict__ mask,
    bf16_t* __restrict__ Xb, bf16_t* __restrict__ Wqb,
    bf16_t* __restrict__ Wkb, bf16_t* __restrict__ Wvb,
    bf16_t* __restrict__ Wob, float* __restrict__ maskl) {
  size_t i = ((size_t)blockIdx.x * 256 + threadIdx.x) * 4;
  const float* src;
  bf16_t* dst;
  size_t off;
  float scale = 1.0f;
  if (i < 8388608) {
    src = X; dst = Xb; off = i;
  } else {
    size_t j = i - 8388608;
    if (j >= 4194304) {
      // mask tail: 8192 floats -> maskl (fp32, scaled by log2e)
      size_t mo = j - 4194304;  // grid sized so mo in [0, 8192)
      float4 mv = *(const float4*)(mask + mo);
      const float LOG2E = 1.4426950408889634f;
      float4 ml = {mv.x * LOG2E, mv.y * LOG2E, mv.z * LOG2E, mv.w * LOG2E};
      *(float4*)(maskl + mo) = ml;
      return;
    }
    int w = (int)(j >> 20);
    off = j & 1048575;
    switch (w) {
      case 0: src = Wq; dst = Wqb; scale = QSCALE; break;
      case 1: src = Wk; dst = Wkb; break;
      case 2: src = Wv; dst = Wvb; break;
      default: src = Wo; dst = Wob; break;
    }
  }
  float4 v = *(const float4*)(src + off);
  bf16x4 o = {(bf16_t)(v.x * scale), (bf16_t)(v.y * scale),
              (bf16_t)(v.z * scale), (bf16_t)(v.w * scale)};
  *(bf16x4*)(dst + off) = o;
}

// ---------------------------------------------------------------------------
// GEMM body (m97 structure): 128x128 tile, BK=64, global_load_lds staging,
// XOR-swizzled LDS, 4 waves (2x2), 32 MFMA / BK. setprio kept (R3 showed
// neutral-to-positive on the GEMM dispatches).
// ---------------------------------------------------------------------------
__device__ __forceinline__ void gemm_core(const bf16_t* __restrict__ A,
                                          const bf16_t* __restrict__ Bw,
                                          int Mb, int Nb, bf16_t* As,
                                          bf16_t* Bs, f32x4 (*acc)[4], int w,
                                          int lane, int quad, int l15, int wm,
                                          int wn) {
  for (int kb = 0; kb < 16; ++kb) {
    stage128(A + (size_t)Mb * 1024 + kb * 64, 1024, As, w, lane);
    stage128(Bw + (size_t)Nb * 1024 + kb * 64, 1024, Bs, w, lane);
    __syncthreads();
#pragma unroll
    for (int kt = 0; kt < 2; ++kt) {
      bf16x8 af[4], bfr[4];
#pragma unroll
      for (int i = 0; i < 4; ++i) {
        af[i] = frag64(As, wm * 64 + i * 16 + l15, kt * 4 + quad);
        bfr[i] = frag64(Bs, wn * 64 + i * 16 + l15, kt * 4 + quad);
      }
      __builtin_amdgcn_s_setprio(1);
#pragma unroll
      for (int mt = 0; mt < 4; ++mt)
#pragma unroll
        for (int nt = 0; nt < 4; ++nt)
          acc[mt][nt] = mfma16(af[mt], bfr[nt], acc[mt][nt]);
      __builtin_amdgcn_s_setprio(0);
    }
    __syncthreads();
  }
}

// ---------------------------------------------------------------------------
// Fused QKV projections, one dispatch. grid (64, 8, 3).
// ---------------------------------------------------------------------------
__global__ __launch_bounds__(256) void gemm_qkv(
    const bf16_t* __restrict__ Xb, const bf16_t* __restrict__ Wqb,
    const bf16_t* __restrict__ Wkb, const bf16_t* __restrict__ Wvb,
    bf16_t* __restrict__ q_ws, bf16_t* __restrict__ k_ws,
    bf16_t* __restrict__ vt_ws) {
  __shared__ __align__(16) bf16_t As[8192];
  __shared__ __align__(16) bf16_t Bs[8192];
  int w = threadIdx.x >> 6, lane = threadIdx.x & 63;
  int quad = lane >> 4, l15 = lane & 15;
  int wm = w >> 1, wn = w & 1;
  int z = blockIdx.z;
  const bf16_t* A = (z == 2) ? Wvb : Xb;
  const bf16_t* Bw = (z == 0) ? Wqb : ((z == 1) ? Wkb : Xb);
  int Mb = (z == 2) ? blockIdx.y * 128 : blockIdx.x * 128;
  int Nb = (z == 2) ? blockIdx.x * 128 : blockIdx.y * 128;
  f32x4 acc[4][4] = {};
  gemm_core(A, Bw, Mb, Nb, As, Bs, acc, w, lane, quad, l15, wm, wn);
  if (z != 2) {
    bf16_t* O = (z == 0) ? q_ws : k_ws;
#pragma unroll
    for (int mt = 0; mt < 4; ++mt) {
      int m0t = Mb + wm * 64 + mt * 16;
#pragma unroll
      for (int nt = 0; nt < 4; ++nt) {
        int n0t = Nb + wn * 64 + nt * 16;
        int h = n0t >> 6, d = (n0t & 63) + l15;
#pragma unroll
        for (int r = 0; r < 4; ++r) {
          int tok = m0t + quad * 4 + r;
          int b = tok >> 11, s = tok & 2047;
          O[(((size_t)b * NH_ + h) * S_ + s) * HD_ + d] = (bf16_t)acc[mt][nt][r];
        }
      }
    }
  } else {
#pragma unroll
    for (int mt = 0; mt < 4; ++mt) {
      int m0t = Mb + wm * 64 + mt * 16;
#pragma unroll
      for (int nt = 0; nt < 4; ++nt) {
        int n0t = Nb + wn * 64 + nt * 16;
#pragma unroll
        for (int r = 0; r < 4; ++r) {
          int dg = m0t + quad * 4 + r;
          int hh = dg >> 6, d = dg & 63;
          int tok = n0t + l15;
          int b = tok >> 11, s = tok & 2047;
          vt_ws[((size_t)(b * NH_ + hh) * HD_ + d) * S_ + s] =
              (bf16_t)acc[mt][nt][r];
        }
      }
    }
  }
}

// ---------------------------------------------------------------------------
// Output projection: out = attn @ Wo^T, fp32 [M,1024]. grid (64, 8).
// ---------------------------------------------------------------------------
__global__ __launch_bounds__(256) void gemm_out(
    const bf16_t* __restrict__ A, const bf16_t* __restrict__ Bw,
    float* __restrict__ out) {
  __shared__ __align__(16) bf16_t As[8192];
  __shared__ __align__(16) bf16_t Bs[8192];
  int w = threadIdx.x >> 6, lane = threadIdx.x & 63;
  int quad = lane >> 4, l15 = lane & 15;
  int wm = w >> 1, wn = w & 1;
  int Mb = blockIdx.x * 128, Nb = blockIdx.y * 128;
  f32x4 acc[4][4] = {};
  gemm_core(A, Bw, Mb, Nb, As, Bs, acc, w, lane, quad, l15, wm, wn);
#pragma unroll
  for (int mt = 0; mt < 4; ++mt) {
    int m0t = Mb + wm * 64 + mt * 16;
#pragma unroll
    for (int nt = 0; nt < 4; ++nt) {
      int n0t = Nb + wn * 64 + nt * 16;
#pragma unroll
      for (int r = 0; r < 4; ++r)
        out[(size_t)(m0t + quad * 4 + r) * 1024 + n0t + l15] = acc[mt][nt][r];
    }
  }
}

// ---------------------------------------------------------------------------
// Flash attention. R5: back to the proven R2 single-barrier double-buffer
// structure, with two clean deltas and NO new register state:
//  (a) K/V staged via global_load_lds (m97 pattern): no kreg/vreg registers,
//      no per-iteration LDS writes, no mid-loop vmcnt stall. Issue chunk c+1
//      at top of iter c into buf^1; the barrier's vmcnt(0) drain at the end
//      of iter c is the wait -> one full compute phase of latency cover.
//      Buf^1 is safe to overwrite: the end-of-previous-iteration barrier
//      guarantees all waves finished reading it.
//  (b) lean exp2 via __ocml_native_exp2_f32 (single v_exp_f32), replacing
//      the denorm-guarded libm lowering (~6 VALU -> 1 per element, 32/lane).
// R4 LESSON: deep reg-prefetch spilled (WRITE_SIZE 256MB). R3 LESSON: asm
// volatile exp2 + attn setprio confounded the lean-VALU test. No setprio in
// attn (lockstep-barrier regime). R1 LESSON: launch_bounds(256,3), not 4.
// P stays in-register (permlane quad-transpose, bank conflicts 0).
// Row sums l[q] via ones-MFMA; normalization in epilogue.
// grid (S/128, B*NH), block 256; LDS 32.8KB -> 4 blocks/CU.
// ---------------------------------------------------------------------------
__global__ __launch_bounds__(256, 3) void attn_fused(
    const bf16_t* __restrict__ Q, const bf16_t* __restrict__ K,
    const bf16_t* __restrict__ Vt, const float* __restrict__ maskl,
    bf16_t* __restrict__ Oa) {
  __shared__ __align__(16) bf16_t Ks[2][4096];
  __shared__ __align__(16) bf16_t Vs[2][4096];
  int w = threadIdx.x >> 6, lane = threadIdx.x & 63;
  int quad = lane >> 4, l15 = lane & 15;
  int bh = blockIdx.y;
  int b = bh >> 4, h = bh & 15;
  int q0 = blockIdx.x * 128 + w * 32;
  const bf16_t* Qh = Q + (size_t)bh * (S_ * HD_);
  const bf16_t* Kh = K + (size_t)bh * (S_ * HD_);
  const bf16_t* Vh = Vt + (size_t)bh * (HD_ * S_);
  const float* mb = maskl + b * S_;  // already log2-domain
  const bf16_t one_b = (bf16_t)1.0f;
  bf16x8 ones = {one_b, one_b, one_b, one_b, one_b, one_b, one_b, one_b};

  // staging geometry: wave w stages segs w*2+j (j=0,1) of each 8KB tile.
  // Per-lane GLOBAL address carries the XOR chunk swizzle; LDS dest is the
  // wave-uniform seg base (gll16 adds lane*16B) -> layout matches frag64.
  int srow[2], schunk[2], lseg[2];
#pragma unroll
  for (int j = 0; j < 2; ++j) {
    int seg = w * 2 + j;
    srow[j] = seg * 8 + (lane >> 3);
    schunk[j] = (lane & 7) ^ (srow[j] & 7);
    lseg[j] = seg * 512;  // elements
  }

  // Q B-frags: [n=q=l15][k=d=quad*8+j], nt in {0,1}, kt in {0,1}
  bf16x8 qf[2][2];
#pragma unroll
  for (int nt = 0; nt < 2; ++nt)
#pragma unroll
    for (int kt = 0; kt < 2; ++kt)
      qf[nt][kt] = *(const bf16x8*)(Qh + (size_t)(q0 + nt * 16 + l15) * HD_ +
                                    kt * 32 + quad * 8);

  f32x4 oc[4][2] = {};
  f32x4 lc[2] = {};  // row-sum accumulators via ones-MFMA (rows identical)

  // prologue: stage chunk 0 into buf0 (async); mask chunk0 -> regs
#pragma unroll
  for (int j = 0; j < 2; ++j) {
    gll16(Kh + (size_t)srow[j] * HD_ + schunk[j] * 8, &Ks[0][0] + lseg[j]);
    gll16(Vh + (size_t)srow[j] * S_ + schunk[j] * 8, &Vs[0][0] + lseg[j]);
  }
  f32x4 mreg[4];
#pragma unroll
  for (int mt = 0; mt < 4; ++mt)
    mreg[mt] = *(const f32x4*)(mb + mt * 16 + quad * 4);
  __syncthreads();  // drains vmcnt -> chunk 0 staged & visible

  for (int c = 0; c < 32; ++c) {
    int cur = c & 1;
    // (1) issue async staging of chunk c+1 into the other buffer
    if (c + 1 < 32) {
      const bf16_t* Kc = Kh + (size_t)(c + 1) * 64 * HD_;
      const bf16_t* Vc = Vh + (size_t)(c + 1) * 64;
#pragma unroll
      for (int j = 0; j < 2; ++j) {
        gll16(Kc + (size_t)srow[j] * HD_ + schunk[j] * 8,
              &Ks[cur ^ 1][0] + lseg[j]);
        gll16(Vc + (size_t)srow[j] * S_ + schunk[j] * 8,
              &Vs[cur ^ 1][0] + lseg[j]);
      }
    }
    // mask: consume prefetched regs; prefetch chunk c+1 (log2-domain)
    f32x4 mcur[4];
#pragma unroll
    for (int mt = 0; mt < 4; ++mt) mcur[mt] = mreg[mt];
    if (c + 1 < 32) {
#pragma unroll
      for (int mt = 0; mt < 4; ++mt)
        mreg[mt] = *(const f32x4*)(mb + (c + 1) * 64 + mt * 16 + quad * 4);
    }
    // (2) S^T = K @ Q^T (log2 domain) : row=key=mt*16+quad*4+r, col=q
    f32x4 sc[4][2] = {};
#pragma unroll
    for (int kt = 0; kt < 2; ++kt) {
      bf16x8 kf[4];
#pragma unroll
      for (int mt = 0; mt < 4; ++mt)
        kf[mt] = frag64(Ks[cur], mt * 16 + l15, kt * 4 + quad);
#pragma unroll
      for (int mt = 0; mt < 4; ++mt)
#pragma unroll
        for (int nt = 0; nt < 2; ++nt)
          sc[mt][nt] = mfma16(kf[mt], qf[nt][kt], sc[mt][nt]);
    }
    // (3) P = exp2(s + maskl), packed + quad-transposed in-register;
    // O^T += Vt @ P^T ; l += ones @ P^T. Scoped per-kt (8 live pk words).
#pragma unroll
    for (int kt = 0; kt < 2; ++kt) {
      unsigned pk[2][2][2];
#pragma unroll
      for (int mi = 0; mi < 2; ++mi) {
        int mt = kt * 2 + mi;
#pragma unroll
        for (int nt = 0; nt < 2; ++nt) {
          f32x4 e = sc[mt][nt] + mcur[mt];
          f32x4 p;
#pragma unroll
          for (int r = 0; r < 4; ++r) p[r] = fast_exp2(e[r]);
          bf16x2t h0 = {(bf16_t)p[0], (bf16_t)p[1]};
          bf16x2t h1 = {(bf16_t)p[2], (bf16_t)p[3]};
          pk[mi][nt][0] = __builtin_bit_cast(unsigned, h0);
          pk[mi][nt][1] = __builtin_bit_cast(unsigned, h1);
        }
      }
      bf16x8 pf[2];
#pragma unroll
      for (int nt = 0; nt < 2; ++nt) {
        u32x2 a0 = __builtin_amdgcn_permlane32_swap(pk[0][nt][0],
                                                    pk[1][nt][0],
                                                    false, false);
        u32x2 b0 = __builtin_amdgcn_permlane16_swap(a0.x, a0.y, false, false);
        u32x2 a1 = __builtin_amdgcn_permlane32_swap(pk[0][nt][1],
                                                    pk[1][nt][1],
                                                    false, false);
        u32x2 b1 = __builtin_amdgcn_permlane16_swap(a1.x, a1.y, false, false);
        // word t: t0=(rr0,s0) t1=(rr1,s0) t2=(rr0,s1) t3=(rr1,s1)
        u32x4 pu = {b0.x, b1.x, b0.y, b1.y};
        pf[nt] = __builtin_bit_cast(bf16x8, pu);
      }
      lc[0] = mfma16(ones, pf[0], lc[0]);
      lc[1] = mfma16(ones, pf[1], lc[1]);
#pragma unroll
      for (int dt = 0; dt < 4; ++dt) {
        bf16x8 vf = frag64(Vs[cur], dt * 16 + l15, kt * 4 + quad);
#pragma unroll
        for (int nt = 0; nt < 2; ++nt)
          oc[dt][nt] = mfma16(vf, pf[nt], oc[dt][nt]);
      }
    }
    // (4) single barrier: drains vmcnt (chunk c+1 staged) and frees buf cur
    __syncthreads();
  }
  // ---- epilogue: O^T/l -> Oa[b, s=q, h*64+d], packed 8B stores ----
  float inv[2] = {1.0f / lc[0][0], 1.0f / lc[1][0]};
#pragma unroll
  for (int dt = 0; dt < 4; ++dt)
#pragma unroll
    for (int nt = 0; nt < 2; ++nt) {
      bf16x4 o4;
#pragma unroll
      for (int r = 0; r < 4; ++r) o4[r] = (bf16_t)(oc[dt][nt][r] * inv[nt]);
      size_t tok = (size_t)b * S_ + q0 + nt * 16 + l15;
      *(bf16x4*)(Oa + tok * H_ + h * HD_ + dt * 16 + quad * 4) = o4;
    }
}

// ---------------------------------------------------------------------------
extern "C" void kernel_launch(void* const* d_in, const int* in_sizes, int n_in,
                              void* d_out, int out_size, void* d_ws,
                              size_t ws_size, hipStream_t stream) {
  const float* hs   = (const float*)d_in[0];
  const float* mask = (const float*)d_in[1];
  const float* Wq   = (const float*)d_in[2];
  const float* Wk   = (const float*)d_in[3];
  const float* Wv   = (const float*)d_in[4];
  const float* Wo   = (const float*)d_in[5];
  float* out = (float*)d_out;

  char* p = (char*)d_ws;
  bf16_t* Xb  = (bf16_t*)p; p += (size_t)8192 * 1024 * 2;
  bf16_t* Wqb = (bf16_t*)p; p += (size_t)1024 * 1024 * 2;
  bf16_t* Wkb = (bf16_t*)p; p += (size_t)1024 * 1024 * 2;
  bf16_t* Wvb = (bf16_t*)p; p += (size_t)1024 * 1024 * 2;
  bf16_t* Wob = (bf16_t*)p; p += (size_t)1024 * 1024 * 2;
  bf16_t* q_ws  = (bf16_t*)p; p += (size_t)8192 * 1024 * 2;  // [B,NH,S,HD]
  bf16_t* k_ws  = (bf16_t*)p; p += (size_t)8192 * 1024 * 2;  // [B,NH,S,HD]
  bf16_t* vt_ws = (bf16_t*)p; p += (size_t)8192 * 1024 * 2;  // [B,NH,HD,S]
  float* maskl = (float*)p; p += (size_t)B_ * S_ * 4;        // log2e-scaled
  bf16_t* attn_b = Xb;  // Xb dead after QKV GEMMs; reuse for attention output

  // grid covers 8M X + 4M weights + 8K mask floats, all /4 per thread
  cvt_all<<<12296, 256, 0, stream>>>(hs, Wq, Wk, Wv, Wo, mask, Xb, Wqb, Wkb,
                                     Wvb, Wob, maskl);
  gemm_qkv<<<dim3(64, 8, 3), 256, 0, stream>>>(Xb, Wqb, Wkb, Wvb, q_ws, k_ws,
                                               vt_ws);
  attn_fused<<<dim3(16, 64), 256, 0, stream>>>(q_ws, k_ws, vt_ws, maskl,
                                               attn_b);
  gemm_out<<<dim3(64, 8), 256, 0, stream>>>(attn_b, Wob, out);
}

// Round 6
// 244.466 us; speedup vs baseline: 1.4970x; 1.1077x over previous
//
#include <hip/hip_runtime.h>
#include <hip/hip_bf16.h>

// Problem constants
#define B_ 4
#define S_ 2048
#define H_ 1024
#define NH_ 16
#define HD_ 64
// HD^-0.5 * log2(e), folded into Wq at cast time -> QK MFMA emits log2-domain
#define QSCALE 0.1803368801111204f

typedef __bf16 bf16_t;
typedef bf16_t bf16x8 __attribute__((ext_vector_type(8)));
typedef bf16_t bf16x4 __attribute__((ext_vector_type(4)));
typedef bf16_t bf16x2t __attribute__((ext_vector_type(2)));
typedef float f32x4 __attribute__((ext_vector_type(4)));
typedef unsigned u32x2 __attribute__((ext_vector_type(2)));
typedef unsigned u32x4 __attribute__((ext_vector_type(4)));

__device__ __forceinline__ f32x4 mfma16(bf16x8 a, bf16x8 b, f32x4 c) {
  return __builtin_amdgcn_mfma_f32_16x16x32_bf16(a, b, c, 0, 0, 0);
}

// Single v_exp_f32 via OCML native (always linked by hipcc; no builtin
// availability gamble, no asm). Flush-to-zero below -126 is exactly right
// for softmax tails.
extern "C" __device__ float __ocml_native_exp2_f32(float);
__device__ __forceinline__ float fast_exp2(float x) {
  return __ocml_native_exp2_f32(x);
}

// async 16B global->LDS. lds ptr must be wave-uniform; HW adds lane*16.
__device__ __forceinline__ void gll16(const bf16_t* g, bf16_t* l) {
  __builtin_amdgcn_global_load_lds(
      (const __attribute__((address_space(1))) void*)g,
      (__attribute__((address_space(3))) void*)l, 16, 0, 0);
}

// Read a 16B A/B fragment from a [rows][64] bf16 LDS tile whose 16B chunks
// are XOR-swizzled: LDS[row][slot] holds global chunk slot^(row&7).
__device__ __forceinline__ bf16x8 frag64(const bf16_t* lds, int row,
                                         int kchunk) {
  return *(const bf16x8*)((const char*)lds + row * 128 +
                          ((kchunk ^ (row & 7)) << 4));
}

// Stage a 128x64 bf16 tile (rows from gbase, row stride gstride elems) into
// a 16KB LDS tile with the XOR chunk swizzle. 4 waves x 4 segs x 1KB.
__device__ __forceinline__ void stage128(const bf16_t* gbase, int gstride,
                                         bf16_t* lds, int w, int lane) {
#pragma unroll
  for (int j = 0; j < 4; ++j) {
    int seg = w * 4 + j;
    int row = seg * 8 + (lane >> 3);
    int chunk = (lane & 7) ^ (row & 7);
    gll16(gbase + (size_t)row * gstride + chunk * 8, lds + seg * 512);
  }
}

// ---------------------------------------------------------------------------
// Cast fp32 -> bf16 for X (8M elems) and the 4 weight matrices (1M each).
// Wq additionally scaled by QSCALE so scores come out in log2 domain.
// Also emits maskl = mask * log2(e) (fp32, B*S).
// ---------------------------------------------------------------------------
__global__ __launch_bounds__(256) void cvt_all(
    const float* __restrict__ X, const float* __restrict__ Wq,
    const float* __restrict__ Wk, const float* __restrict__ Wv,
    const float* __restrict__ Wo, const float* __restrict__ mask,
    bf16_t* __restrict__ Xb, bf16_t* __restrict__ Wqb,
    bf16_t* __restrict__ Wkb, bf16_t* __restrict__ Wvb,
    bf16_t* __restrict__ Wob, float* __restrict__ maskl) {
  size_t i = ((size_t)blockIdx.x * 256 + threadIdx.x) * 4;
  const float* src;
  bf16_t* dst;
  size_t off;
  float scale = 1.0f;
  if (i < 8388608) {
    src = X; dst = Xb; off = i;
  } else {
    size_t j = i - 8388608;
    if (j >= 4194304) {
      // mask tail: 8192 floats -> maskl (fp32, scaled by log2e)
      size_t mo = j - 4194304;  // grid sized so mo in [0, 8192)
      float4 mv = *(const float4*)(mask + mo);
      const float LOG2E = 1.4426950408889634f;
      float4 ml = {mv.x * LOG2E, mv.y * LOG2E, mv.z * LOG2E, mv.w * LOG2E};
      *(float4*)(maskl + mo) = ml;
      return;
    }
    int w = (int)(j >> 20);
    off = j & 1048575;
    switch (w) {
      case 0: src = Wq; dst = Wqb; scale = QSCALE; break;
      case 1: src = Wk; dst = Wkb; break;
      case 2: src = Wv; dst = Wvb; break;
      default: src = Wo; dst = Wob; break;
    }
  }
  float4 v = *(const float4*)(src + off);
  bf16x4 o = {(bf16_t)(v.x * scale), (bf16_t)(v.y * scale),
              (bf16_t)(v.z * scale), (bf16_t)(v.w * scale)};
  *(bf16x4*)(dst + off) = o;
}

// ---------------------------------------------------------------------------
// GEMM body (m97 structure): 128x128 tile, BK=64, global_load_lds staging,
// XOR-swizzled LDS, 4 waves (2x2), 32 MFMA / BK. setprio kept (R3 showed
// neutral-to-positive on the GEMM dispatches).
// ---------------------------------------------------------------------------
__device__ __forceinline__ void gemm_core(const bf16_t* __restrict__ A,
                                          const bf16_t* __restrict__ Bw,
                                          int Mb, int Nb, bf16_t* As,
                                          bf16_t* Bs, f32x4 (*acc)[4], int w,
                                          int lane, int quad, int l15, int wm,
                                          int wn) {
  for (int kb = 0; kb < 16; ++kb) {
    stage128(A + (size_t)Mb * 1024 + kb * 64, 1024, As, w, lane);
    stage128(Bw + (size_t)Nb * 1024 + kb * 64, 1024, Bs, w, lane);
    __syncthreads();
#pragma unroll
    for (int kt = 0; kt < 2; ++kt) {
      bf16x8 af[4], bfr[4];
#pragma unroll
      for (int i = 0; i < 4; ++i) {
        af[i] = frag64(As, wm * 64 + i * 16 + l15, kt * 4 + quad);
        bfr[i] = frag64(Bs, wn * 64 + i * 16 + l15, kt * 4 + quad);
      }
      __builtin_amdgcn_s_setprio(1);
#pragma unroll
      for (int mt = 0; mt < 4; ++mt)
#pragma unroll
        for (int nt = 0; nt < 4; ++nt)
          acc[mt][nt] = mfma16(af[mt], bfr[nt], acc[mt][nt]);
      __builtin_amdgcn_s_setprio(0);
    }
    __syncthreads();
  }
}

// ---------------------------------------------------------------------------
// Fused QKV projections, one dispatch. grid (64, 8, 3).
// ---------------------------------------------------------------------------
__global__ __launch_bounds__(256) void gemm_qkv(
    const bf16_t* __restrict__ Xb, const bf16_t* __restrict__ Wqb,
    const bf16_t* __restrict__ Wkb, const bf16_t* __restrict__ Wvb,
    bf16_t* __restrict__ q_ws, bf16_t* __restrict__ k_ws,
    bf16_t* __restrict__ vt_ws) {
  __shared__ __align__(16) bf16_t As[8192];
  __shared__ __align__(16) bf16_t Bs[8192];
  int w = threadIdx.x >> 6, lane = threadIdx.x & 63;
  int quad = lane >> 4, l15 = lane & 15;
  int wm = w >> 1, wn = w & 1;
  int z = blockIdx.z;
  const bf16_t* A = (z == 2) ? Wvb : Xb;
  const bf16_t* Bw = (z == 0) ? Wqb : ((z == 1) ? Wkb : Xb);
  int Mb = (z == 2) ? blockIdx.y * 128 : blockIdx.x * 128;
  int Nb = (z == 2) ? blockIdx.x * 128 : blockIdx.y * 128;
  f32x4 acc[4][4] = {};
  gemm_core(A, Bw, Mb, Nb, As, Bs, acc, w, lane, quad, l15, wm, wn);
  if (z != 2) {
    bf16_t* O = (z == 0) ? q_ws : k_ws;
#pragma unroll
    for (int mt = 0; mt < 4; ++mt) {
      int m0t = Mb + wm * 64 + mt * 16;
#pragma unroll
      for (int nt = 0; nt < 4; ++nt) {
        int n0t = Nb + wn * 64 + nt * 16;
        int h = n0t >> 6, d = (n0t & 63) + l15;
#pragma unroll
        for (int r = 0; r < 4; ++r) {
          int tok = m0t + quad * 4 + r;
          int b = tok >> 11, s = tok & 2047;
          O[(((size_t)b * NH_ + h) * S_ + s) * HD_ + d] = (bf16_t)acc[mt][nt][r];
        }
      }
    }
  } else {
#pragma unroll
    for (int mt = 0; mt < 4; ++mt) {
      int m0t = Mb + wm * 64 + mt * 16;
#pragma unroll
      for (int nt = 0; nt < 4; ++nt) {
        int n0t = Nb + wn * 64 + nt * 16;
#pragma unroll
        for (int r = 0; r < 4; ++r) {
          int dg = m0t + quad * 4 + r;
          int hh = dg >> 6, d = dg & 63;
          int tok = n0t + l15;
          int b = tok >> 11, s = tok & 2047;
          vt_ws[((size_t)(b * NH_ + hh) * HD_ + d) * S_ + s] =
              (bf16_t)acc[mt][nt][r];
        }
      }
    }
  }
}

// ---------------------------------------------------------------------------
// Output projection: out = attn @ Wo^T, fp32 [M,1024]. grid (64, 8).
// ---------------------------------------------------------------------------
__global__ __launch_bounds__(256) void gemm_out(
    const bf16_t* __restrict__ A, const bf16_t* __restrict__ Bw,
    float* __restrict__ out) {
  __shared__ __align__(16) bf16_t As[8192];
  __shared__ __align__(16) bf16_t Bs[8192];
  int w = threadIdx.x >> 6, lane = threadIdx.x & 63;
  int quad = lane >> 4, l15 = lane & 15;
  int wm = w >> 1, wn = w & 1;
  int Mb = blockIdx.x * 128, Nb = blockIdx.y * 128;
  f32x4 acc[4][4] = {};
  gemm_core(A, Bw, Mb, Nb, As, Bs, acc, w, lane, quad, l15, wm, wn);
#pragma unroll
  for (int mt = 0; mt < 4; ++mt) {
    int m0t = Mb + wm * 64 + mt * 16;
#pragma unroll
    for (int nt = 0; nt < 4; ++nt) {
      int n0t = Nb + wn * 64 + nt * 16;
#pragma unroll
      for (int r = 0; r < 4; ++r)
        out[(size_t)(m0t + quad * 4 + r) * 1024 + n0t + l15] = acc[mt][nt][r];
    }
  }
}

// ---------------------------------------------------------------------------
// Flash attention. R6 on top of the R5 win (110us):
//  (a) 8-wave blocks, 256 q-rows/block: per-wave staging halves (2 gll16 vs
//      4 per chunk), barrier count per q-row halves, K/V HBM fetch halves.
//      LDS unchanged (32.8KB: K/V only), per-wave compute identical.
//  (b) grid (bh=64, qchunk=8), bh = blockIdx.x (dispatch-fastest): all 8
//      q-blocks of head b have linear ids == b (mod 64 -> mod 8), so they
//      round-robin to the SAME XCD -> K/V (512KB/head) cached once per L2
//      (8 heads x 512KB = 4MB = one XCD L2), not replicated 8x.
//  (c) mask as QK MFMA C-init: sc[mt][nt] initialized to maskl[key] (row
//      index of the C layout == key) instead of 0 -> the MFMA emits
//      s+maskl directly; deletes 32 v_add + mcur copies per chunk.
// Kept: global_load_lds staging (R5), in-register P via permlane quad-
// transpose (bank conflicts 0), ocml native exp2, no setprio (lockstep),
// single barrier per chunk (vmcnt drain = staging wait, issued a full
// compute phase earlier). launch_bounds(512,2): VGPR cap 256, loose --
// avoids R1's forced-low-tier spill disaster.
// grid (64, 8), block 512; LDS 32.8KB.
// ---------------------------------------------------------------------------
__global__ __launch_bounds__(512, 2) void attn_fused(
    const bf16_t* __restrict__ Q, const bf16_t* __restrict__ K,
    const bf16_t* __restrict__ Vt, const float* __restrict__ maskl,
    bf16_t* __restrict__ Oa) {
  __shared__ __align__(16) bf16_t Ks[2][4096];
  __shared__ __align__(16) bf16_t Vs[2][4096];
  int w = threadIdx.x >> 6, lane = threadIdx.x & 63;  // w in 0..7
  int quad = lane >> 4, l15 = lane & 15;
  int bh = blockIdx.x;  // head index dispatch-fastest -> XCD affinity
  int b = bh >> 4, h = bh & 15;
  int q0 = blockIdx.y * 256 + w * 32;
  const bf16_t* Qh = Q + (size_t)bh * (S_ * HD_);
  const bf16_t* Kh = K + (size_t)bh * (S_ * HD_);
  const bf16_t* Vh = Vt + (size_t)bh * (HD_ * S_);
  const float* mb = maskl + b * S_;  // already log2-domain
  const bf16_t one_b = (bf16_t)1.0f;
  bf16x8 ones = {one_b, one_b, one_b, one_b, one_b, one_b, one_b, one_b};

  // staging geometry: wave w stages seg w (1KB) of the K tile and of the V
  // tile. Per-lane GLOBAL address carries the XOR chunk swizzle; LDS dest is
  // the wave-uniform seg base (gll16 adds lane*16B) -> matches frag64.
  int srow = w * 8 + (lane >> 3);
  int schunk = (lane & 7) ^ (srow & 7);
  int lseg = w * 512;  // elements

  // Q B-frags: [n=q=l15][k=d=quad*8+j], nt in {0,1}, kt in {0,1}
  bf16x8 qf[2][2];
#pragma unroll
  for (int nt = 0; nt < 2; ++nt)
#pragma unroll
    for (int kt = 0; kt < 2; ++kt)
      qf[nt][kt] = *(const bf16x8*)(Qh + (size_t)(q0 + nt * 16 + l15) * HD_ +
                                    kt * 32 + quad * 8);

  f32x4 oc[4][2] = {};
  f32x4 lc[2] = {};  // row-sum accumulators via ones-MFMA (rows identical)

  // prologue: stage chunk 0 into buf0 (async); mask chunk0 -> regs
  gll16(Kh + (size_t)srow * HD_ + schunk * 8, &Ks[0][0] + lseg);
  gll16(Vh + (size_t)srow * S_ + schunk * 8, &Vs[0][0] + lseg);
  f32x4 mreg[4];
#pragma unroll
  for (int mt = 0; mt < 4; ++mt)
    mreg[mt] = *(const f32x4*)(mb + mt * 16 + quad * 4);
  __syncthreads();  // drains vmcnt -> chunk 0 staged & visible

  for (int c = 0; c < 32; ++c) {
    int cur = c & 1;
    // (1) issue async staging of chunk c+1 into the other buffer
    if (c + 1 < 32) {
      const bf16_t* Kc = Kh + (size_t)(c + 1) * 64 * HD_;
      const bf16_t* Vc = Vt == nullptr ? nullptr : Vh + (size_t)(c + 1) * 64;
      gll16(Kc + (size_t)srow * HD_ + schunk * 8, &Ks[cur ^ 1][0] + lseg);
      gll16(Vc + (size_t)srow * S_ + schunk * 8, &Vs[cur ^ 1][0] + lseg);
    }
    // (2) S^T = K @ Q^T + maskl (log2 domain). C-init = maskl[key]: the C
    // layout row (mt*16+quad*4+r) IS the key index, matching mreg[mt][r].
    f32x4 sc[4][2];
#pragma unroll
    for (int mt = 0; mt < 4; ++mt)
#pragma unroll
      for (int nt = 0; nt < 2; ++nt) sc[mt][nt] = mreg[mt];
    // mask prefetch for chunk c+1 (log2-domain)
    if (c + 1 < 32) {
#pragma unroll
      for (int mt = 0; mt < 4; ++mt)
        mreg[mt] = *(const f32x4*)(mb + (c + 1) * 64 + mt * 16 + quad * 4);
    }
#pragma unroll
    for (int kt = 0; kt < 2; ++kt) {
      bf16x8 kf[4];
#pragma unroll
      for (int mt = 0; mt < 4; ++mt)
        kf[mt] = frag64(Ks[cur], mt * 16 + l15, kt * 4 + quad);
#pragma unroll
      for (int mt = 0; mt < 4; ++mt)
#pragma unroll
        for (int nt = 0; nt < 2; ++nt)
          sc[mt][nt] = mfma16(kf[mt], qf[nt][kt], sc[mt][nt]);
    }
    // (3) P = exp2(sc), packed + quad-transposed in-register;
    // O^T += Vt @ P^T ; l += ones @ P^T. Scoped per-kt (8 live pk words).
#pragma unroll
    for (int kt = 0; kt < 2; ++kt) {
      unsigned pk[2][2][2];
#pragma unroll
      for (int mi = 0; mi < 2; ++mi) {
        int mt = kt * 2 + mi;
#pragma unroll
        for (int nt = 0; nt < 2; ++nt) {
          f32x4 p;
#pragma unroll
          for (int r = 0; r < 4; ++r) p[r] = fast_exp2(sc[mt][nt][r]);
          bf16x2t h0 = {(bf16_t)p[0], (bf16_t)p[1]};
          bf16x2t h1 = {(bf16_t)p[2], (bf16_t)p[3]};
          pk[mi][nt][0] = __builtin_bit_cast(unsigned, h0);
          pk[mi][nt][1] = __builtin_bit_cast(unsigned, h1);
        }
      }
      bf16x8 pf[2];
#pragma unroll
      for (int nt = 0; nt < 2; ++nt) {
        u32x2 a0 = __builtin_amdgcn_permlane32_swap(pk[0][nt][0],
                                                    pk[1][nt][0],
                                                    false, false);
        u32x2 b0 = __builtin_amdgcn_permlane16_swap(a0.x, a0.y, false, false);
        u32x2 a1 = __builtin_amdgcn_permlane32_swap(pk[0][nt][1],
                                                    pk[1][nt][1],
                                                    false, false);
        u32x2 b1 = __builtin_amdgcn_permlane16_swap(a1.x, a1.y, false, false);
        // word t: t0=(rr0,s0) t1=(rr1,s0) t2=(rr0,s1) t3=(rr1,s1)
        u32x4 pu = {b0.x, b1.x, b0.y, b1.y};
        pf[nt] = __builtin_bit_cast(bf16x8, pu);
      }
      lc[0] = mfma16(ones, pf[0], lc[0]);
      lc[1] = mfma16(ones, pf[1], lc[1]);
#pragma unroll
      for (int dt = 0; dt < 4; ++dt) {
        bf16x8 vf = frag64(Vs[cur], dt * 16 + l15, kt * 4 + quad);
#pragma unroll
        for (int nt = 0; nt < 2; ++nt)
          oc[dt][nt] = mfma16(vf, pf[nt], oc[dt][nt]);
      }
    }
    // (4) single barrier: drains vmcnt (chunk c+1 staged) and frees buf cur
    __syncthreads();
  }
  // ---- epilogue: O^T/l -> Oa[b, s=q, h*64+d], packed 8B stores ----
  float inv[2] = {1.0f / lc[0][0], 1.0f / lc[1][0]};
#pragma unroll
  for (int dt = 0; dt < 4; ++dt)
#pragma unroll
    for (int nt = 0; nt < 2; ++nt) {
      bf16x4 o4;
#pragma unroll
      for (int r = 0; r < 4; ++r) o4[r] = (bf16_t)(oc[dt][nt][r] * inv[nt]);
      size_t tok = (size_t)b * S_ + q0 + nt * 16 + l15;
      *(bf16x4*)(Oa + tok * H_ + h * HD_ + dt * 16 + quad * 4) = o4;
    }
}

// ---------------------------------------------------------------------------
extern "C" void kernel_launch(void* const* d_in, const int* in_sizes, int n_in,
                              void* d_out, int out_size, void* d_ws,
                              size_t ws_size, hipStream_t stream) {
  const float* hs   = (const float*)d_in[0];
  const float* mask = (const float*)d_in[1];
  const float* Wq   = (const float*)d_in[2];
  const float* Wk   = (const float*)d_in[3];
  const float* Wv   = (const float*)d_in[4];
  const float* Wo   = (const float*)d_in[5];
  float* out = (float*)d_out;

  char* p = (char*)d_ws;
  bf16_t* Xb  = (bf16_t*)p; p += (size_t)8192 * 1024 * 2;
  bf16_t* Wqb = (bf16_t*)p; p += (size_t)1024 * 1024 * 2;
  bf16_t* Wkb = (bf16_t*)p; p += (size_t)1024 * 1024 * 2;
  bf16_t* Wvb = (bf16_t*)p; p += (size_t)1024 * 1024 * 2;
  bf16_t* Wob = (bf16_t*)p; p += (size_t)1024 * 1024 * 2;
  bf16_t* q_ws  = (bf16_t*)p; p += (size_t)8192 * 1024 * 2;  // [B,NH,S,HD]
  bf16_t* k_ws  = (bf16_t*)p; p += (size_t)8192 * 1024 * 2;  // [B,NH,S,HD]
  bf16_t* vt_ws = (bf16_t*)p; p += (size_t)8192 * 1024 * 2;  // [B,NH,HD,S]
  float* maskl = (float*)p; p += (size_t)B_ * S_ * 4;        // log2e-scaled
  bf16_t* attn_b = Xb;  // Xb dead after QKV GEMMs; reuse for attention output

  // grid covers 8M X + 4M weights + 8K mask floats, all /4 per thread
  cvt_all<<<12296, 256, 0, stream>>>(hs, Wq, Wk, Wv, Wo, mask, Xb, Wqb, Wkb,
                                     Wvb, Wob, maskl);
  gemm_qkv<<<dim3(64, 8, 3), 256, 0, stream>>>(Xb, Wqb, Wkb, Wvb, q_ws, k_ws,
                                               vt_ws);
  attn_fused<<<dim3(64, 8), 512, 0, stream>>>(q_ws, k_ws, vt_ws, maskl,
                                              attn_b);
  gemm_out<<<dim3(64, 8), 256, 0, stream>>>(attn_b, Wob, out);
}